// Round 5
// baseline (271.188 us; speedup 1.0000x reference)
//
#include <hip/hip_runtime.h>

// out[n, :] = sum_{l=0..7} weight[l, x[n,l], :]
// N=131072, L=8, K=1024, D=1024; f32 in/out.
//
// Round 5: weights converted once per call to bf16 in d_ws (16 MB), halving
// the L2-resident gather traffic (4 GB -> 2 GB). XCD slicing kept: D split
// into 8 slices of 128 cols, block b -> slice b%8, so each XCD's L2 holds its
// 2 MB bf16 weight slice. Indices LDS-staged, read as int4; 16 gathers in
// flight; f32 accumulate; NT stores. f32 fallback if ws_size < 16 MB.

#define N_ROWS 131072
#define L_DIM 8
#define K_DIM 1024
#define D_DIM 1024

#define NXCD 8
#define ROWS_PER_BLOCK 128
#define CHUNKS (N_ROWS / ROWS_PER_BLOCK)   // 1024
#define W_ELEMS (L_DIM * K_DIM * D_DIM)    // 8,388,608

typedef float        f32x4 __attribute__((ext_vector_type(4)));
typedef unsigned int u32x4 __attribute__((ext_vector_type(4)));

__device__ __forceinline__ unsigned short f2bf_rne(float f) {
    unsigned u = __float_as_uint(f);
    unsigned r = u + 0x7fffu + ((u >> 16) & 1u);   // round-to-nearest-even
    return (unsigned short)(r >> 16);
}
__device__ __forceinline__ float bflo(unsigned u) { return __uint_as_float(u << 16); }
__device__ __forceinline__ float bfhi(unsigned u) { return __uint_as_float(u & 0xffff0000u); }

// ---- pass 1: f32 weight -> bf16 scratch --------------------------------
__global__ __launch_bounds__(256) void convert_w_bf16(
    const float* __restrict__ w, unsigned short* __restrict__ wb)
{
    const int i = blockIdx.x * 256 + threadIdx.x;       // one thread per 4 floats
    const f32x4 v = __builtin_nontemporal_load(
        reinterpret_cast<const f32x4*>(w) + i);
    ushort4 o;
    o.x = f2bf_rne(v.x); o.y = f2bf_rne(v.y);
    o.z = f2bf_rne(v.z); o.w = f2bf_rne(v.w);
    reinterpret_cast<ushort4*>(wb)[i] = o;
}

// ---- pass 2: gather+sum from bf16 weights ------------------------------
__global__ __launch_bounds__(256) void gather_sum_bf16(
    const int* __restrict__ x,
    const unsigned short* __restrict__ wb,
    float* __restrict__ out)
{
    __shared__ int4 sx[ROWS_PER_BLOCK * 2];             // 128 rows x 8 idx

    const int slice = blockIdx.x & (NXCD - 1);          // -> XCD id
    const int chunk = blockIdx.x >> 3;
    const int t     = threadIdx.x;
    const int n0    = chunk * ROWS_PER_BLOCK;

    sx[t] = reinterpret_cast<const int4*>(x + (size_t)n0 * L_DIM)[t];
    __syncthreads();

    const int rg = t >> 4;                              // row-group 0..15
    const int ln = t & 15;                              // 16 lanes x 8 cols = 128
    const int col = slice * 128 + ln * 8;
    const unsigned short* __restrict__ wbase = wb + col;

    #pragma unroll
    for (int i = 0; i < 4; ++i) {
        const int rA = rg + 32 * i;
        const int rB = rA + 16;
        const int4 iA0 = sx[rA * 2], iA1 = sx[rA * 2 + 1];
        const int4 iB0 = sx[rB * 2], iB1 = sx[rB * 2 + 1];
        const int kA[8] = {iA0.x, iA0.y, iA0.z, iA0.w, iA1.x, iA1.y, iA1.z, iA1.w};
        const int kB[8] = {iB0.x, iB0.y, iB0.z, iB0.w, iB1.x, iB1.y, iB1.z, iB1.w};

        u32x4 vA[L_DIM], vB[L_DIM];
        #pragma unroll
        for (int l = 0; l < L_DIM; ++l)
            vA[l] = *reinterpret_cast<const u32x4*>(
                wbase + (size_t)(l * K_DIM + kA[l]) * D_DIM);
        #pragma unroll
        for (int l = 0; l < L_DIM; ++l)
            vB[l] = *reinterpret_cast<const u32x4*>(
                wbase + (size_t)(l * K_DIM + kB[l]) * D_DIM);

        f32x4 a0 = (f32x4)(0.f), a1 = (f32x4)(0.f);
        f32x4 b0 = (f32x4)(0.f), b1 = (f32x4)(0.f);
        #pragma unroll
        for (int l = 0; l < L_DIM; ++l) {
            const u32x4 ua = vA[l];
            a0.x += bflo(ua[0]); a0.y += bfhi(ua[0]);
            a0.z += bflo(ua[1]); a0.w += bfhi(ua[1]);
            a1.x += bflo(ua[2]); a1.y += bfhi(ua[2]);
            a1.z += bflo(ua[3]); a1.w += bfhi(ua[3]);
            const u32x4 ub = vB[l];
            b0.x += bflo(ub[0]); b0.y += bfhi(ub[0]);
            b0.z += bflo(ub[1]); b0.w += bfhi(ub[1]);
            b1.x += bflo(ub[2]); b1.y += bfhi(ub[2]);
            b1.z += bflo(ub[3]); b1.w += bfhi(ub[3]);
        }

        float* opA = out + (size_t)(n0 + rA) * D_DIM + col;
        float* opB = out + (size_t)(n0 + rB) * D_DIM + col;
        __builtin_nontemporal_store(a0, reinterpret_cast<f32x4*>(opA));
        __builtin_nontemporal_store(a1, reinterpret_cast<f32x4*>(opA + 4));
        __builtin_nontemporal_store(b0, reinterpret_cast<f32x4*>(opB));
        __builtin_nontemporal_store(b1, reinterpret_cast<f32x4*>(opB + 4));
    }
}

// ---- fallback: round-4 f32 kernel (used when ws too small) -------------
__global__ __launch_bounds__(256) void gather_sum_f32(
    const int* __restrict__ x,
    const float* __restrict__ w,
    float* __restrict__ out)
{
    __shared__ int sxi[ROWS_PER_BLOCK * L_DIM];
    const int slice = blockIdx.x & (NXCD - 1);
    const int chunk = blockIdx.x >> 3;
    const int t     = threadIdx.x;
    const int n0    = chunk * ROWS_PER_BLOCK;

    reinterpret_cast<int4*>(sxi)[t] =
        reinterpret_cast<const int4*>(x + (size_t)n0 * L_DIM)[t];
    __syncthreads();

    const int rg   = t >> 5;
    const int lane = t & 31;
    const int col  = slice * 128 + lane * 4;
    const float* __restrict__ wbase = w + col;

    #pragma unroll
    for (int i = 0; i < 8; ++i) {
        const int rA = rg + 16 * i;
        const int rB = rA + 8;
        const int* xA = sxi + rA * L_DIM;
        const int* xB = sxi + rB * L_DIM;
        f32x4 vA[L_DIM], vB[L_DIM];
        #pragma unroll
        for (int l = 0; l < L_DIM; ++l)
            vA[l] = *reinterpret_cast<const f32x4*>(
                wbase + (size_t)(l * K_DIM + xA[l]) * D_DIM);
        #pragma unroll
        for (int l = 0; l < L_DIM; ++l)
            vB[l] = *reinterpret_cast<const f32x4*>(
                wbase + (size_t)(l * K_DIM + xB[l]) * D_DIM);
        f32x4 accA = ((vA[0] + vA[1]) + (vA[2] + vA[3]))
                   + ((vA[4] + vA[5]) + (vA[6] + vA[7]));
        f32x4 accB = ((vB[0] + vB[1]) + (vB[2] + vB[3]))
                   + ((vB[4] + vB[5]) + (vB[6] + vB[7]));
        __builtin_nontemporal_store(accA,
            reinterpret_cast<f32x4*>(out + (size_t)(n0 + rA) * D_DIM + col));
        __builtin_nontemporal_store(accB,
            reinterpret_cast<f32x4*>(out + (size_t)(n0 + rB) * D_DIM + col));
    }
}

extern "C" void kernel_launch(void* const* d_in, const int* in_sizes, int n_in,
                              void* d_out, int out_size, void* d_ws, size_t ws_size,
                              hipStream_t stream)
{
    const int*   x = (const int*)d_in[0];     // (N, L) int32
    const float* w = (const float*)d_in[1];   // (L, K, D) f32
    float* out = (float*)d_out;               // (N, D) f32

    if (ws_size >= (size_t)W_ELEMS * 2) {
        unsigned short* wb = (unsigned short*)d_ws;
        convert_w_bf16<<<W_ELEMS / 4 / 256, 256, 0, stream>>>(w, wb);
        gather_sum_bf16<<<CHUNKS * NXCD, 256, 0, stream>>>(x, wb, out);
    } else {
        gather_sum_f32<<<CHUNKS * NXCD, 256, 0, stream>>>(x, w, out);
    }
}

// Round 6
// 159.759 us; speedup vs baseline: 1.6975x; 1.6975x over previous
//
#include <hip/hip_runtime.h>

// out[n, :] = sum_{l=0..7} weight[l, x[n,l], :]
// N=131072, L=8, K=1024, D=1024; f32 in/out.
//
// Round 6: round-4 structure (which hit the L2 line-throughput limit) with
// bf16 gather loads. Weights converted once per call to bf16 in d_ws (16 MB).
// Lane owns 4 output cols: gathers are 8B (dwordx2) bf16 loads -> read lines
// halve vs f32; stores are unchanged from round 4 (32 lanes x 16B = 512B
// contiguous per NT-store instruction -- round 5's regression was the
// strided half-line store pattern, not the bf16 idea).

#define N_ROWS 131072
#define L_DIM 8
#define K_DIM 1024
#define D_DIM 1024

#define NXCD 8
#define ROWS_PER_BLOCK 128
#define CHUNKS (N_ROWS / ROWS_PER_BLOCK)   // 1024
#define W_ELEMS (L_DIM * K_DIM * D_DIM)    // 8,388,608

typedef float        f32x4 __attribute__((ext_vector_type(4)));
typedef unsigned int u32x2 __attribute__((ext_vector_type(2)));

__device__ __forceinline__ unsigned short f2bf_rne(float f) {
    unsigned u = __float_as_uint(f);
    unsigned r = u + 0x7fffu + ((u >> 16) & 1u);   // round-to-nearest-even
    return (unsigned short)(r >> 16);
}
__device__ __forceinline__ float bflo(unsigned u) { return __uint_as_float(u << 16); }
__device__ __forceinline__ float bfhi(unsigned u) { return __uint_as_float(u & 0xffff0000u); }

// ---- pass 1: f32 weight -> bf16 scratch --------------------------------
__global__ __launch_bounds__(256) void convert_w_bf16(
    const float* __restrict__ w, unsigned short* __restrict__ wb)
{
    const int i = blockIdx.x * 256 + threadIdx.x;       // one thread per 4 floats
    const f32x4 v = __builtin_nontemporal_load(
        reinterpret_cast<const f32x4*>(w) + i);
    ushort4 o;
    o.x = f2bf_rne(v.x); o.y = f2bf_rne(v.y);
    o.z = f2bf_rne(v.z); o.w = f2bf_rne(v.w);
    reinterpret_cast<ushort4*>(wb)[i] = o;
}

// ---- pass 2: gather+sum from bf16 weights ------------------------------
__global__ __launch_bounds__(256) void gather_sum_bf16(
    const int* __restrict__ x,
    const unsigned short* __restrict__ wb,
    float* __restrict__ out)
{
    __shared__ int sxi[ROWS_PER_BLOCK * L_DIM];         // 4 KB of indices

    const int slice = blockIdx.x & (NXCD - 1);          // -> XCD id
    const int chunk = blockIdx.x >> 3;
    const int t     = threadIdx.x;
    const int n0    = chunk * ROWS_PER_BLOCK;

    reinterpret_cast<int4*>(sxi)[t] =
        reinterpret_cast<const int4*>(x + (size_t)n0 * L_DIM)[t];
    __syncthreads();

    const int rg   = t >> 5;                            // row-group 0..7
    const int lane = t & 31;                            // 32 lanes x 4 cols = 128
    const int col  = slice * 128 + lane * 4;
    const unsigned short* __restrict__ wbase = wb + col;

    #pragma unroll
    for (int i = 0; i < 8; ++i) {
        const int rA = rg + 16 * i;                     // two rows per iteration
        const int rB = rA + 8;
        const int* xA = sxi + rA * L_DIM;
        const int* xB = sxi + rB * L_DIM;

        // Issue all 16 gathers (8B bf16 each) before consuming any.
        u32x2 vA[L_DIM], vB[L_DIM];
        #pragma unroll
        for (int l = 0; l < L_DIM; ++l)
            vA[l] = *reinterpret_cast<const u32x2*>(
                wbase + (size_t)(l * K_DIM + xA[l]) * D_DIM);
        #pragma unroll
        for (int l = 0; l < L_DIM; ++l)
            vB[l] = *reinterpret_cast<const u32x2*>(
                wbase + (size_t)(l * K_DIM + xB[l]) * D_DIM);

        f32x4 accA = (f32x4)(0.f), accB = (f32x4)(0.f);
        #pragma unroll
        for (int l = 0; l < L_DIM; ++l) {
            accA.x += bflo(vA[l][0]); accA.y += bfhi(vA[l][0]);
            accA.z += bflo(vA[l][1]); accA.w += bfhi(vA[l][1]);
            accB.x += bflo(vB[l][0]); accB.y += bfhi(vB[l][0]);
            accB.z += bflo(vB[l][1]); accB.w += bfhi(vB[l][1]);
        }

        // Stores identical to round 4: 32 lanes x 16B contiguous per instr.
        __builtin_nontemporal_store(accA,
            reinterpret_cast<f32x4*>(out + (size_t)(n0 + rA) * D_DIM + col));
        __builtin_nontemporal_store(accB,
            reinterpret_cast<f32x4*>(out + (size_t)(n0 + rB) * D_DIM + col));
    }
}

// ---- fallback: round-4 f32 kernel (used when ws too small) -------------
__global__ __launch_bounds__(256) void gather_sum_f32(
    const int* __restrict__ x,
    const float* __restrict__ w,
    float* __restrict__ out)
{
    __shared__ int sxi[ROWS_PER_BLOCK * L_DIM];
    const int slice = blockIdx.x & (NXCD - 1);
    const int chunk = blockIdx.x >> 3;
    const int t     = threadIdx.x;
    const int n0    = chunk * ROWS_PER_BLOCK;

    reinterpret_cast<int4*>(sxi)[t] =
        reinterpret_cast<const int4*>(x + (size_t)n0 * L_DIM)[t];
    __syncthreads();

    const int rg   = t >> 5;
    const int lane = t & 31;
    const int col  = slice * 128 + lane * 4;
    const float* __restrict__ wbase = w + col;

    #pragma unroll
    for (int i = 0; i < 8; ++i) {
        const int rA = rg + 16 * i;
        const int rB = rA + 8;
        const int* xA = sxi + rA * L_DIM;
        const int* xB = sxi + rB * L_DIM;
        f32x4 vA[L_DIM], vB[L_DIM];
        #pragma unroll
        for (int l = 0; l < L_DIM; ++l)
            vA[l] = *reinterpret_cast<const f32x4*>(
                wbase + (size_t)(l * K_DIM + xA[l]) * D_DIM);
        #pragma unroll
        for (int l = 0; l < L_DIM; ++l)
            vB[l] = *reinterpret_cast<const f32x4*>(
                wbase + (size_t)(l * K_DIM + xB[l]) * D_DIM);
        f32x4 accA = ((vA[0] + vA[1]) + (vA[2] + vA[3]))
                   + ((vA[4] + vA[5]) + (vA[6] + vA[7]));
        f32x4 accB = ((vB[0] + vB[1]) + (vB[2] + vB[3]))
                   + ((vB[4] + vB[5]) + (vB[6] + vB[7]));
        __builtin_nontemporal_store(accA,
            reinterpret_cast<f32x4*>(out + (size_t)(n0 + rA) * D_DIM + col));
        __builtin_nontemporal_store(accB,
            reinterpret_cast<f32x4*>(out + (size_t)(n0 + rB) * D_DIM + col));
    }
}

extern "C" void kernel_launch(void* const* d_in, const int* in_sizes, int n_in,
                              void* d_out, int out_size, void* d_ws, size_t ws_size,
                              hipStream_t stream)
{
    const int*   x = (const int*)d_in[0];     // (N, L) int32
    const float* w = (const float*)d_in[1];   // (L, K, D) f32
    float* out = (float*)d_out;               // (N, D) f32

    if (ws_size >= (size_t)W_ELEMS * 2) {
        unsigned short* wb = (unsigned short*)d_ws;
        convert_w_bf16<<<W_ELEMS / 4 / 256, 256, 0, stream>>>(w, wb);
        gather_sum_bf16<<<CHUNKS * NXCD, 256, 0, stream>>>(x, wb, out);
    } else {
        gather_sum_f32<<<CHUNKS * NXCD, 256, 0, stream>>>(x, w, out);
    }
}

// Round 7
// 156.804 us; speedup vs baseline: 1.7295x; 1.0188x over previous
//
#include <hip/hip_runtime.h>

// out[n, :] = sum_{l=0..7} weight[l, x[n,l], :]
// N=131072, L=8, K=1024, D=1024; f32 in/out.
//
// Round 7: round-6 (bf16 gathers, XCD slicing, LDS indices, round-4 store
// layout) with deeper MLP: 4 rows / 32 gathers (256 B/lane) in flight per
// iteration, and 32-bit byte-offset addressing off a uniform base.

#define N_ROWS 131072
#define L_DIM 8
#define K_DIM 1024
#define D_DIM 1024

#define NXCD 8
#define ROWS_PER_BLOCK 128
#define CHUNKS (N_ROWS / ROWS_PER_BLOCK)   // 1024
#define W_ELEMS (L_DIM * K_DIM * D_DIM)    // 8,388,608

typedef float        f32x4 __attribute__((ext_vector_type(4)));
typedef unsigned int u32x2 __attribute__((ext_vector_type(2)));

__device__ __forceinline__ unsigned short f2bf_rne(float f) {
    unsigned u = __float_as_uint(f);
    unsigned r = u + 0x7fffu + ((u >> 16) & 1u);   // round-to-nearest-even
    return (unsigned short)(r >> 16);
}
__device__ __forceinline__ float bflo(unsigned u) { return __uint_as_float(u << 16); }
__device__ __forceinline__ float bfhi(unsigned u) { return __uint_as_float(u & 0xffff0000u); }

// ---- pass 1: f32 weight -> bf16 scratch --------------------------------
__global__ __launch_bounds__(256) void convert_w_bf16(
    const float* __restrict__ w, unsigned short* __restrict__ wb)
{
    const int i = blockIdx.x * 256 + threadIdx.x;       // one thread per 4 floats
    const f32x4 v = __builtin_nontemporal_load(
        reinterpret_cast<const f32x4*>(w) + i);
    ushort4 o;
    o.x = f2bf_rne(v.x); o.y = f2bf_rne(v.y);
    o.z = f2bf_rne(v.z); o.w = f2bf_rne(v.w);
    reinterpret_cast<ushort4*>(wb)[i] = o;
}

// ---- pass 2: gather+sum from bf16 weights ------------------------------
__global__ __launch_bounds__(256) void gather_sum_bf16(
    const int* __restrict__ x,
    const unsigned short* __restrict__ wb,
    float* __restrict__ out)
{
    __shared__ int sxi[ROWS_PER_BLOCK * L_DIM];         // 4 KB of indices

    const int slice = blockIdx.x & (NXCD - 1);          // -> XCD id
    const int chunk = blockIdx.x >> 3;
    const int t     = threadIdx.x;
    const int n0    = chunk * ROWS_PER_BLOCK;

    reinterpret_cast<int4*>(sxi)[t] =
        reinterpret_cast<const int4*>(x + (size_t)n0 * L_DIM)[t];
    __syncthreads();

    const int rg   = t >> 5;                            // row-group 0..7
    const int lane = t & 31;                            // 32 lanes x 4 cols = 128
    const int col  = slice * 128 + lane * 4;
    const unsigned colb = (unsigned)col * 2u;           // byte offset of column
    const char* __restrict__ wbytes = (const char*)wb;

    #pragma unroll
    for (int i = 0; i < 4; ++i) {
        // 4 rows this iteration: rg + 8*(4i+j), j=0..3
        u32x2 v[4][L_DIM];
        #pragma unroll
        for (int j = 0; j < 4; ++j) {
            const int r = rg + 8 * (4 * i + j);
            const int* __restrict__ xr = sxi + r * L_DIM;
            #pragma unroll
            for (int l = 0; l < L_DIM; ++l) {
                // byte offset = (col + (l*K + k)*D) * 2, fits in 32 bits
                const unsigned off = colb +
                    (((unsigned)(l * K_DIM) + (unsigned)xr[l]) << 11);
                v[j][l] = *reinterpret_cast<const u32x2*>(wbytes + off);
            }
        }

        #pragma unroll
        for (int j = 0; j < 4; ++j) {
            const int r = rg + 8 * (4 * i + j);
            f32x4 acc = (f32x4)(0.f);
            #pragma unroll
            for (int l = 0; l < L_DIM; ++l) {
                acc.x += bflo(v[j][l][0]); acc.y += bfhi(v[j][l][0]);
                acc.z += bflo(v[j][l][1]); acc.w += bfhi(v[j][l][1]);
            }
            __builtin_nontemporal_store(acc,
                reinterpret_cast<f32x4*>(out + (size_t)(n0 + r) * D_DIM + col));
        }
    }
}

// ---- fallback: round-4 f32 kernel (used when ws too small) -------------
__global__ __launch_bounds__(256) void gather_sum_f32(
    const int* __restrict__ x,
    const float* __restrict__ w,
    float* __restrict__ out)
{
    __shared__ int sxi[ROWS_PER_BLOCK * L_DIM];
    const int slice = blockIdx.x & (NXCD - 1);
    const int chunk = blockIdx.x >> 3;
    const int t     = threadIdx.x;
    const int n0    = chunk * ROWS_PER_BLOCK;

    reinterpret_cast<int4*>(sxi)[t] =
        reinterpret_cast<const int4*>(x + (size_t)n0 * L_DIM)[t];
    __syncthreads();

    const int rg   = t >> 5;
    const int lane = t & 31;
    const int col  = slice * 128 + lane * 4;
    const float* __restrict__ wbase = w + col;

    #pragma unroll
    for (int i = 0; i < 8; ++i) {
        const int rA = rg + 16 * i;
        const int rB = rA + 8;
        const int* xA = sxi + rA * L_DIM;
        const int* xB = sxi + rB * L_DIM;
        f32x4 vA[L_DIM], vB[L_DIM];
        #pragma unroll
        for (int l = 0; l < L_DIM; ++l)
            vA[l] = *reinterpret_cast<const f32x4*>(
                wbase + (size_t)(l * K_DIM + xA[l]) * D_DIM);
        #pragma unroll
        for (int l = 0; l < L_DIM; ++l)
            vB[l] = *reinterpret_cast<const f32x4*>(
                wbase + (size_t)(l * K_DIM + xB[l]) * D_DIM);
        f32x4 accA = ((vA[0] + vA[1]) + (vA[2] + vA[3]))
                   + ((vA[4] + vA[5]) + (vA[6] + vA[7]));
        f32x4 accB = ((vB[0] + vB[1]) + (vB[2] + vB[3]))
                   + ((vB[4] + vB[5]) + (vB[6] + vB[7]));
        __builtin_nontemporal_store(accA,
            reinterpret_cast<f32x4*>(out + (size_t)(n0 + rA) * D_DIM + col));
        __builtin_nontemporal_store(accB,
            reinterpret_cast<f32x4*>(out + (size_t)(n0 + rB) * D_DIM + col));
    }
}

extern "C" void kernel_launch(void* const* d_in, const int* in_sizes, int n_in,
                              void* d_out, int out_size, void* d_ws, size_t ws_size,
                              hipStream_t stream)
{
    const int*   x = (const int*)d_in[0];     // (N, L) int32
    const float* w = (const float*)d_in[1];   // (L, K, D) f32
    float* out = (float*)d_out;               // (N, D) f32

    if (ws_size >= (size_t)W_ELEMS * 2) {
        unsigned short* wb = (unsigned short*)d_ws;
        convert_w_bf16<<<W_ELEMS / 4 / 256, 256, 0, stream>>>(w, wb);
        gather_sum_bf16<<<CHUNKS * NXCD, 256, 0, stream>>>(x, wb, out);
    } else {
        gather_sum_f32<<<CHUNKS * NXCD, 256, 0, stream>>>(x, w, out);
    }
}

// Round 8
// 152.572 us; speedup vs baseline: 1.7775x; 1.0277x over previous
//
#include <hip/hip_runtime.h>

// out[n, :] = sum_{l=0..7} weight[l, x[n,l], :]
// N=131072, L=8, K=1024, D=1024; f32 in/out.
//
// Round 8: gathered reads staged global->LDS via __builtin_amdgcn_global_load_lds
// (width 16). One wave instruction fetches FOUR gathered 256 B bf16 rows
// (16 lanes x 16 B each) with zero VGPR cost -> outstanding bytes no longer
// VGPR-capped. Double-buffered 16-row chunks; __syncthreads() per chunk is the
// DMA fence (compiler emits vmcnt(0) before s_barrier). Keeps: XCD D-slicing
// (slice = blockIdx&7), bf16 weight table in d_ws, bf16 unpack in f32,
// round-4 contiguous NT store layout.

#define N_ROWS 131072
#define L_DIM 8
#define K_DIM 1024
#define D_DIM 1024

#define NXCD 8
#define RPB 128                       // rows per block
#define CR 16                        // rows per chunk
#define NCH (RPB / CR)               // 8 chunks
#define GRID_CHUNKS (N_ROWS / RPB)   // 1024
#define W_ELEMS (L_DIM * K_DIM * D_DIM)

typedef float        f32x4 __attribute__((ext_vector_type(4)));
typedef unsigned int u32x2 __attribute__((ext_vector_type(2)));

__device__ __forceinline__ unsigned short f2bf_rne(float f) {
    unsigned u = __float_as_uint(f);
    unsigned r = u + 0x7fffu + ((u >> 16) & 1u);   // round-to-nearest-even
    return (unsigned short)(r >> 16);
}
__device__ __forceinline__ float bflo(unsigned u) { return __uint_as_float(u << 16); }
__device__ __forceinline__ float bfhi(unsigned u) { return __uint_as_float(u & 0xffff0000u); }

__device__ __forceinline__ void load_lds16(const void* g, void* l) {
    __builtin_amdgcn_global_load_lds(
        (const __attribute__((address_space(1))) void*)g,
        (__attribute__((address_space(3))) void*)l,
        16, 0, 0);
}

// ---- pass 1: f32 weight -> bf16 scratch --------------------------------
__global__ __launch_bounds__(256) void convert_w_bf16(
    const float* __restrict__ w, unsigned short* __restrict__ wb)
{
    const int i = blockIdx.x * 256 + threadIdx.x;       // one thread per 4 floats
    const f32x4 v = __builtin_nontemporal_load(
        reinterpret_cast<const f32x4*>(w) + i);
    ushort4 o;
    o.x = f2bf_rne(v.x); o.y = f2bf_rne(v.y);
    o.z = f2bf_rne(v.z); o.w = f2bf_rne(v.w);
    reinterpret_cast<ushort4*>(wb)[i] = o;
}

// ---- pass 2: DMA-staged gather+sum -------------------------------------
__global__ __launch_bounds__(256) void gather_sum_dma(
    const int* __restrict__ x,
    const unsigned short* __restrict__ wb,
    float* __restrict__ out)
{
    __shared__ int sxi[RPB * L_DIM];                       // 4 KB indices
    __shared__ __align__(1024) char buf[2][CR * L_DIM * 256]; // 2 x 32 KB

    const int slice = blockIdx.x & (NXCD - 1);             // -> XCD id
    const int chunk = blockIdx.x >> 3;
    const int t     = threadIdx.x;
    const int n0    = chunk * RPB;

    if (t < RPB * L_DIM / 4)
        reinterpret_cast<int4*>(sxi)[t] =
            reinterpret_cast<const int4*>(x + (size_t)n0 * L_DIM)[t];
    __syncthreads();

    const int w_id = t >> 6;                               // wave 0..3
    const int lam  = t & 63;
    const int grp  = lam >> 4;                             // 0..3: row within quad
    const int sub  = lam & 15;                             // 16 B unit within row
    const int half = (t >> 5) & 1;
    const int lane = t & 31;

    const unsigned colb = (unsigned)slice << 8;            // slice*128 cols *2 B
    const char* __restrict__ wbytes = (const char*)wb;

    // ---- prologue: DMA chunk 0 into buf[0] ----
    #pragma unroll
    for (int i = 0; i < 8; ++i) {
        const int j = w_id * 8 + i;                        // 0..31
        const int g = 4 * j + grp;                         // gathered row 0..127
        const int l = g & 7;
        const int k = sxi[g];
        const unsigned off = (((unsigned)((l << 10) + k)) << 11) + colb
                           + (unsigned)sub * 16u;
        load_lds16(wbytes + off, &buf[0][j * 1024]);
    }
    __syncthreads();                                       // vmcnt(0) + barrier

    #pragma unroll
    for (int c = 0; c < NCH; ++c) {
        // issue DMA for chunk c+1 into the other buffer
        if (c + 1 < NCH) {
            #pragma unroll
            for (int i = 0; i < 8; ++i) {
                const int j = w_id * 8 + i;
                const int g = 4 * j + grp;
                const int l = g & 7;
                const int k = sxi[(c + 1) * 128 + g];
                const unsigned off = (((unsigned)((l << 10) + k)) << 11) + colb
                                   + (unsigned)sub * 16u;
                load_lds16(wbytes + off, &buf[(c + 1) & 1][j * 1024]);
            }
        }

        // consume chunk c from buf[c&1]; each wave owns rows [4w, 4w+4)
        const char* __restrict__ rb = buf[c & 1];
        #pragma unroll
        for (int s = 0; s < 2; ++s) {
            const int r = w_id * 4 + s * 2 + half;         // 0..15
            u32x2 v[L_DIM];
            #pragma unroll
            for (int l = 0; l < L_DIM; ++l)
                v[l] = *reinterpret_cast<const u32x2*>(
                    rb + (r * 8 + l) * 256 + lane * 8);

            f32x4 acc = (f32x4)(0.f);
            #pragma unroll
            for (int l = 0; l < L_DIM; ++l) {
                acc.x += bflo(v[l][0]); acc.y += bfhi(v[l][0]);
                acc.z += bflo(v[l][1]); acc.w += bfhi(v[l][1]);
            }

            const int n = n0 + c * CR + r;
            __builtin_nontemporal_store(acc,
                reinterpret_cast<f32x4*>(
                    out + (size_t)n * D_DIM + slice * 128 + lane * 4));
        }

        __syncthreads();   // drains this wave's DMAs (vmcnt(0)) + aligns waves
    }
}

// ---- fallback: round-4 f32 kernel (used when ws too small) -------------
__global__ __launch_bounds__(256) void gather_sum_f32(
    const int* __restrict__ x,
    const float* __restrict__ w,
    float* __restrict__ out)
{
    __shared__ int sxi[RPB * L_DIM];
    const int slice = blockIdx.x & (NXCD - 1);
    const int chunk = blockIdx.x >> 3;
    const int t     = threadIdx.x;
    const int n0    = chunk * RPB;

    if (t < RPB * L_DIM / 4)
        reinterpret_cast<int4*>(sxi)[t] =
            reinterpret_cast<const int4*>(x + (size_t)n0 * L_DIM)[t];
    __syncthreads();

    const int rg   = t >> 5;
    const int lane = t & 31;
    const int col  = slice * 128 + lane * 4;
    const float* __restrict__ wbase = w + col;

    #pragma unroll
    for (int i = 0; i < 8; ++i) {
        const int rA = rg + 16 * i;
        const int rB = rA + 8;
        const int* xA = sxi + rA * L_DIM;
        const int* xB = sxi + rB * L_DIM;
        f32x4 vA[L_DIM], vB[L_DIM];
        #pragma unroll
        for (int l = 0; l < L_DIM; ++l)
            vA[l] = *reinterpret_cast<const f32x4*>(
                wbase + (size_t)(l * K_DIM + xA[l]) * D_DIM);
        #pragma unroll
        for (int l = 0; l < L_DIM; ++l)
            vB[l] = *reinterpret_cast<const f32x4*>(
                wbase + (size_t)(l * K_DIM + xB[l]) * D_DIM);
        f32x4 accA = ((vA[0] + vA[1]) + (vA[2] + vA[3]))
                   + ((vA[4] + vA[5]) + (vA[6] + vA[7]));
        f32x4 accB = ((vB[0] + vB[1]) + (vB[2] + vB[3]))
                   + ((vB[4] + vB[5]) + (vB[6] + vB[7]));
        __builtin_nontemporal_store(accA,
            reinterpret_cast<f32x4*>(out + (size_t)(n0 + rA) * D_DIM + col));
        __builtin_nontemporal_store(accB,
            reinterpret_cast<f32x4*>(out + (size_t)(n0 + rB) * D_DIM + col));
    }
}

extern "C" void kernel_launch(void* const* d_in, const int* in_sizes, int n_in,
                              void* d_out, int out_size, void* d_ws, size_t ws_size,
                              hipStream_t stream)
{
    const int*   x = (const int*)d_in[0];     // (N, L) int32
    const float* w = (const float*)d_in[1];   // (L, K, D) f32
    float* out = (float*)d_out;               // (N, D) f32

    if (ws_size >= (size_t)W_ELEMS * 2) {
        unsigned short* wb = (unsigned short*)d_ws;
        convert_w_bf16<<<W_ELEMS / 4 / 256, 256, 0, stream>>>(w, wb);
        gather_sum_dma<<<GRID_CHUNKS * NXCD, 256, 0, stream>>>(x, wb, out);
    } else {
        gather_sum_f32<<<GRID_CHUNKS * NXCD, 256, 0, stream>>>(x, w, out);
    }
}

// Round 9
// 145.643 us; speedup vs baseline: 1.8620x; 1.0476x over previous
//
#include <hip/hip_runtime.h>

// out[n, :] = sum_{l=0..7} weight[l, x[n,l], :]
// N=131072, L=8, K=1024, D=1024; f32 in/out.
//
// Round 9: two changes vs round 8.
// (1) Channel-spread rotation: bf16 table stored with each (l,k) row rotated
//     by ((l+k)&7)*128 cols, so XCD j's 256 B read window moves per row ->
//     L2 channel address bits vary (was: fixed slice<<8 offset mod 2 KB).
//     Working set per XCD stays 2 MB (one window per row) -> L2-resident.
// (2) Barrier-free per-wave pipeline: each wave DMAs exactly the rows it
//     consumes (global_load_lds, width 16, zero VGPR), chunk = 8 output rows,
//     prefetch depth 2, 3 LDS buffers, counted s_waitcnt vmcnt(N) per chunk
//     (N derived from issue order: 4 loads + 1 store per iter per wave).
//     No __syncthreads in the main loop.

#define N_ROWS 131072
#define L_DIM 8
#define K_DIM 1024
#define D_DIM 1024

#define NXCD 8
#define RPB 128                      // output rows per block
#define CR 8                         // output rows per chunk
#define NCH (RPB / CR)               // 16 chunks
#define PFD 2                        // prefetch depth (chunks)
#define NBUF (PFD + 1)               // LDS buffers
#define CHB (CR * L_DIM * 256)       // bytes per chunk buffer = 16384
#define GRID_CHUNKS (N_ROWS / RPB)   // 1024
#define W_ELEMS (L_DIM * K_DIM * D_DIM)

typedef float        f32x4 __attribute__((ext_vector_type(4)));
typedef unsigned int u32x2 __attribute__((ext_vector_type(2)));

__device__ __forceinline__ unsigned short f2bf_rne(float f) {
    unsigned u = __float_as_uint(f);
    unsigned r = u + 0x7fffu + ((u >> 16) & 1u);   // round-to-nearest-even
    return (unsigned short)(r >> 16);
}
__device__ __forceinline__ float bflo(unsigned u) { return __uint_as_float(u << 16); }
__device__ __forceinline__ float bfhi(unsigned u) { return __uint_as_float(u & 0xffff0000u); }

__device__ __forceinline__ void load_lds16(const void* g, void* l) {
    __builtin_amdgcn_global_load_lds(
        (const __attribute__((address_space(1))) void*)g,
        (__attribute__((address_space(3))) void*)l,
        16, 0, 0);
}

template <int N>
__device__ __forceinline__ void vm_wait() {
    asm volatile("s_waitcnt vmcnt(%0)" :: "n"(N) : "memory");
    __builtin_amdgcn_sched_barrier(0);
}

// loads newer than chunk c's: chunks c+1..min(c+PFD,NCH-1), 4 instrs each;
// stores newer: min(PFD, c). (per-wave issue order: [4 loads][wait][store])
constexpr int waitn(int c) {
    int nl = (c + PFD <= NCH - 1) ? PFD : (NCH - 1 - c);
    int ns = (c < PFD) ? c : PFD;
    return 4 * nl + ns;
}

// ---- pass 1: f32 weight -> rotated bf16 scratch ------------------------
__global__ __launch_bounds__(256) void convert_w_bf16(
    const float* __restrict__ w, unsigned short* __restrict__ wb)
{
    const int i = blockIdx.x * 256 + threadIdx.x;       // 4 floats per thread
    const f32x4 v = __builtin_nontemporal_load(
        reinterpret_cast<const f32x4*>(w) + i);
    ushort4 o;
    o.x = f2bf_rne(v.x); o.y = f2bf_rne(v.y);
    o.z = f2bf_rne(v.z); o.w = f2bf_rne(v.w);

    const int rk = i >> 8;                              // (l,k) row id
    const int c0 = (i & 255) * 4;                       // col of first elem
    const int l  = rk >> 10;
    const int k  = rk & 1023;
    const int r  = (l + k) & 7;
    const int c2 = (c0 + r * 128) & 1023;               // rotated col
    *reinterpret_cast<ushort4*>(wb + ((size_t)rk << 10) + c2) = o;
}

// ---- pass 2: barrier-free pipelined gather+sum -------------------------
__global__ __launch_bounds__(256) void gather_sum_pipe(
    const int* __restrict__ x,
    const unsigned short* __restrict__ wb,
    float* __restrict__ out)
{
    __shared__ int sxi[RPB * L_DIM];                    // 4 KB indices
    __shared__ __align__(1024) char buf[NBUF * CHB];    // 3 x 16 KB

    const int slice = blockIdx.x & (NXCD - 1);          // -> XCD id
    const int chunk = blockIdx.x >> 3;
    const int t     = threadIdx.x;
    const int n0    = chunk * RPB;

    reinterpret_cast<int4*>(sxi)[t] =
        reinterpret_cast<const int4*>(x + (size_t)n0 * L_DIM)[t];
    __syncthreads();                                    // only barrier

    const int w_id = t >> 6;                            // wave 0..3
    const int lam  = t & 63;
    const int grp  = lam >> 4;                          // row within quad
    const int sub  = lam & 15;                          // 16 B unit in window
    const int half = (t >> 5) & 1;
    const int lane = t & 31;

    const char* __restrict__ wbytes = (const char*)wb;

    // issue chunk c's DMA: wave w stages gathered rows g in [16w, 16w+16)
    auto issue = [&](int c) {
        char* __restrict__ db = buf + (c % NBUF) * CHB;
        #pragma unroll
        for (int i = 0; i < 4; ++i) {
            const int j = w_id * 4 + i;                 // 0..15
            const int g = 4 * j + grp;                  // gathered row 0..63
            const int l = g & 7;
            const int k = sxi[c * 64 + g];
            const int r = (slice + l + k) & 7;          // rotated window
            const unsigned off =
                ((unsigned)((l << 10) + k) << 11) + ((unsigned)r << 8)
                + (unsigned)sub * 16u;
            load_lds16(wbytes + off, db + j * 1024);
        }
    };

    auto consume = [&](int c) {
        const char* __restrict__ rb = buf + (c % NBUF) * CHB;
        const int g0 = w_id * 16 + half * 8;            // wave-half's row base
        u32x2 v[L_DIM];
        #pragma unroll
        for (int l = 0; l < L_DIM; ++l)
            v[l] = *reinterpret_cast<const u32x2*>(
                rb + (g0 + l) * 256 + lane * 8);
        f32x4 acc = (f32x4)(0.f);
        #pragma unroll
        for (int l = 0; l < L_DIM; ++l) {
            acc.x += bflo(v[l][0]); acc.y += bfhi(v[l][0]);
            acc.z += bflo(v[l][1]); acc.w += bfhi(v[l][1]);
        }
        const int n = n0 + c * CR + 2 * w_id + half;
        __builtin_nontemporal_store(acc,
            reinterpret_cast<f32x4*>(
                out + (size_t)n * D_DIM + slice * 128 + lane * 4));
    };

    issue(0);
    issue(1);

#define STEP(c)                                   \
    {                                             \
        if ((c) + PFD < NCH) issue((c) + PFD);    \
        vm_wait<waitn(c)>();                      \
        consume(c);                               \
    }
    STEP(0)  STEP(1)  STEP(2)  STEP(3)
    STEP(4)  STEP(5)  STEP(6)  STEP(7)
    STEP(8)  STEP(9)  STEP(10) STEP(11)
    STEP(12) STEP(13) STEP(14) STEP(15)
#undef STEP
}

// ---- fallback: round-4 f32 kernel (used when ws too small) -------------
__global__ __launch_bounds__(256) void gather_sum_f32(
    const int* __restrict__ x,
    const float* __restrict__ w,
    float* __restrict__ out)
{
    __shared__ int sxi[RPB * L_DIM];
    const int slice = blockIdx.x & (NXCD - 1);
    const int chunk = blockIdx.x >> 3;
    const int t     = threadIdx.x;
    const int n0    = chunk * RPB;

    reinterpret_cast<int4*>(sxi)[t] =
        reinterpret_cast<const int4*>(x + (size_t)n0 * L_DIM)[t];
    __syncthreads();

    const int rg   = t >> 5;
    const int lane = t & 31;
    const int col  = slice * 128 + lane * 4;
    const float* __restrict__ wbase = w + col;

    #pragma unroll
    for (int i = 0; i < 8; ++i) {
        const int rA = rg + 16 * i;
        const int rB = rA + 8;
        const int* xA = sxi + rA * L_DIM;
        const int* xB = sxi + rB * L_DIM;
        f32x4 vA[L_DIM], vB[L_DIM];
        #pragma unroll
        for (int l = 0; l < L_DIM; ++l)
            vA[l] = *reinterpret_cast<const f32x4*>(
                wbase + (size_t)(l * K_DIM + xA[l]) * D_DIM);
        #pragma unroll
        for (int l = 0; l < L_DIM; ++l)
            vB[l] = *reinterpret_cast<const f32x4*>(
                wbase + (size_t)(l * K_DIM + xB[l]) * D_DIM);
        f32x4 accA = ((vA[0] + vA[1]) + (vA[2] + vA[3]))
                   + ((vA[4] + vA[5]) + (vA[6] + vA[7]));
        f32x4 accB = ((vB[0] + vB[1]) + (vB[2] + vB[3]))
                   + ((vB[4] + vB[5]) + (vB[6] + vB[7]));
        __builtin_nontemporal_store(accA,
            reinterpret_cast<f32x4*>(out + (size_t)(n0 + rA) * D_DIM + col));
        __builtin_nontemporal_store(accB,
            reinterpret_cast<f32x4*>(out + (size_t)(n0 + rB) * D_DIM + col));
    }
}

extern "C" void kernel_launch(void* const* d_in, const int* in_sizes, int n_in,
                              void* d_out, int out_size, void* d_ws, size_t ws_size,
                              hipStream_t stream)
{
    const int*   x = (const int*)d_in[0];     // (N, L) int32
    const float* w = (const float*)d_in[1];   // (L, K, D) f32
    float* out = (float*)d_out;               // (N, D) f32

    if (ws_size >= (size_t)W_ELEMS * 2) {
        unsigned short* wb = (unsigned short*)d_ws;
        convert_w_bf16<<<W_ELEMS / 4 / 256, 256, 0, stream>>>(w, wb);
        gather_sum_pipe<<<GRID_CHUNKS * NXCD, 256, 0, stream>>>(x, wb, out);
    } else {
        gather_sum_f32<<<GRID_CHUNKS * NXCD, 256, 0, stream>>>(x, w, out);
    }
}